// Round 1
// baseline (146.990 us; speedup 1.0000x reference)
//
#include <hip/hip_runtime.h>

typedef __bf16 bf16_t;
typedef __bf16 bf16x8 __attribute__((ext_vector_type(8)));
typedef __bf16 bf16x4 __attribute__((ext_vector_type(4)));
typedef _Float16 f16x2 __attribute__((ext_vector_type(2)));
typedef _Float16 f16x4 __attribute__((ext_vector_type(4)));
typedef _Float16 f16x8 __attribute__((ext_vector_type(8)));
typedef float f32x4 __attribute__((ext_vector_type(4)));

#define B_   2
#define T_   2048
#define C_   768
#define NH_  12
#define HS_  64
#define N3_  2304
#define M_   4096
#define QSCALE 0.18033688011112042f   // 0.125 * log2(e), folded into Q at GEMM epilogue

__device__ __forceinline__ bf16_t f2bf(float f) {
  unsigned u = __builtin_bit_cast(unsigned, f);
  u += 0x7fffu + ((u >> 16) & 1u);           // round-to-nearest-even
  unsigned short s = (unsigned short)(u >> 16);
  return __builtin_bit_cast(bf16_t, s);
}

// ---------------- fused casts: x fp32->bf16, w fp32 [K][N] -> wt bf16 [N][K] ----------------
__global__ __launch_bounds__(256) void cvt_xw_kernel(const float* __restrict__ x,
                                                     const float* __restrict__ w,
                                                     bf16_t* __restrict__ xb,
                                                     bf16_t* __restrict__ wt) {
  __shared__ float tile[32][33];
  int bx = blockIdx.x;
  if (bx < 3072) {
    int i = (bx * 256 + threadIdx.x) * 4;
    float4 v = *reinterpret_cast<const float4*>(x + i);
    xb[i + 0] = f2bf(v.x);
    xb[i + 1] = f2bf(v.y);
    xb[i + 2] = f2bf(v.z);
    xb[i + 3] = f2bf(v.w);
  } else {
    int b = bx - 3072;                 // 0..1727
    int k0 = (b % 24) * 32, n0 = (b / 24) * 32;
    int tx = threadIdx.x & 31, ty = threadIdx.x >> 5;   // 32 x 8
#pragma unroll
    for (int i = 0; i < 4; i++)
      tile[ty + i * 8][tx] = w[(size_t)(k0 + ty + i * 8) * N3_ + n0 + tx];
    __syncthreads();
#pragma unroll
    for (int i = 0; i < 4; i++)
      wt[(size_t)(n0 + ty + i * 8) * C_ + k0 + tx] = f2bf(tile[tx][ty + i * 8]);
  }
}

// ---------------- qkv GEMM: 2-phase cross-iteration double-buffered pipeline (T3-min) -------
// R14: baseline was load -> drain-barrier -> compute -> barrier per K-step: global->LDS
// latency serially exposed (MfmaUtil 11%, VALUBusy 7.8%, ~310 TF) and only 2.25 blocks/CU
// to hide it. Now: per K-step issue global_load_lds for step t+1 into buf^1 FIRST, then
// ds_read+MFMA on buf, then one __syncthreads() (compiler emits the vmcnt(0) drain there).
// Loads overlap the whole compute phase (m230-V0 682 TF structure). BK=32 dbuf keeps LDS
// at 32 KiB (occupancy unchanged) and the m97 64B-row bank-friendly panel layout; FP
// accumulation order is identical to R13 (two 32-halves in order), so results are bitwise
// unchanged. q/k blocks: swapped operands -> C^T tiles -> 8B packed [t][d] stores, q
// pre-scaled. v blocks: normal -> f16 MFMA-native VA layout for attn PV A-operand.
__global__ __launch_bounds__(256) void gemm_qkv(const bf16_t* __restrict__ xb,
                                                const bf16_t* __restrict__ wt,
                                                const float* __restrict__ bias,
                                                bf16_t* __restrict__ qout,
                                                bf16_t* __restrict__ kout,
                                                _Float16* __restrict__ va) {
  __shared__ bf16_t As[2][128 * 32];   // [buf][m][k] panels, flat, no pad (64B rows)
  __shared__ bf16_t Bs[2][128 * 32];
  const int tid = threadIdx.x;
  const int lane = tid & 63, wave = tid >> 6;
  const int wm = wave >> 1, wn = wave & 1;
  const int quad = lane >> 4, l15 = lane & 15;
  const int row0 = blockIdx.y * 128;
  const int col0 = blockIdx.x * 128;
  const bool isqk = (col0 < 1536);

  f32x4 acc[4][4];
#pragma unroll
  for (int mi = 0; mi < 4; mi++)
#pragma unroll
    for (int ni = 0; ni < 4; ni++) acc[mi][ni] = f32x4{0.f, 0.f, 0.f, 0.f};

  // staging geometry: tile = 128 rows x 32 cols bf16 = 8 KiB = 512 x 16B chunks.
  // thread handles chunks tid and 256+tid; chunk n -> LDS row n>>2, 8-col group n&3.
  // LDS dest is wave-uniform base + lane*16 (glds requirement); global src matches.
  const int r0 = tid >> 2, q0 = tid & 3;
  const int r1 = (256 + tid) >> 2, q1 = (256 + tid) & 3;
  const bf16_t* gA0 = xb + (size_t)(row0 + r0) * C_ + q0 * 8;
  const bf16_t* gA1 = xb + (size_t)(row0 + r1) * C_ + q1 * 8;
  const bf16_t* gB0 = wt + (size_t)(col0 + r0) * C_ + q0 * 8;
  const bf16_t* gB1 = wt + (size_t)(col0 + r1) * C_ + q1 * 8;
  const int ldsOff0 = (wave * 64) * 16;          // chunk block c=0
  const int ldsOff1 = (256 + wave * 64) * 16;    // chunk block c=1

  auto STAGE = [&](int buf, int k0) {
    __builtin_amdgcn_global_load_lds((const __attribute__((address_space(1))) void*)(gA0 + k0),
                                     (__attribute__((address_space(3))) void*)((char*)As[buf] + ldsOff0), 16, 0, 0);
    __builtin_amdgcn_global_load_lds((const __attribute__((address_space(1))) void*)(gA1 + k0),
                                     (__attribute__((address_space(3))) void*)((char*)As[buf] + ldsOff1), 16, 0, 0);
    __builtin_amdgcn_global_load_lds((const __attribute__((address_space(1))) void*)(gB0 + k0),
                                     (__attribute__((address_space(3))) void*)((char*)Bs[buf] + ldsOff0), 16, 0, 0);
    __builtin_amdgcn_global_load_lds((const __attribute__((address_space(1))) void*)(gB1 + k0),
                                     (__attribute__((address_space(3))) void*)((char*)Bs[buf] + ldsOff1), 16, 0, 0);
  };

  STAGE(0, 0);
  __syncthreads();               // drain prologue loads (compiler: vmcnt(0) before barrier)

  constexpr int NT = C_ / 32;    // 24 K-steps
#pragma unroll 2
  for (int t = 0; t < NT; ++t) {
    const int cur = t & 1;
    if (t + 1 < NT) STAGE(cur ^ 1, (t + 1) * 32);   // issue next-tile loads FIRST

    bf16x8 af[4], bfr[4];
#pragma unroll
    for (int mi = 0; mi < 4; mi++)
      af[mi] = *reinterpret_cast<const bf16x8*>(&As[cur][(wm * 64 + mi * 16 + l15) * 32 + quad * 8]);
#pragma unroll
    for (int ni = 0; ni < 4; ni++)
      bfr[ni] = *reinterpret_cast<const bf16x8*>(&Bs[cur][(wn * 64 + ni * 16 + l15) * 32 + quad * 8]);
    if (isqk) {
#pragma unroll
      for (int mi = 0; mi < 4; mi++)
#pragma unroll
        for (int ni = 0; ni < 4; ni++)
          acc[mi][ni] = __builtin_amdgcn_mfma_f32_16x16x32_bf16(bfr[ni], af[mi], acc[mi][ni], 0, 0, 0);
    } else {
#pragma unroll
      for (int mi = 0; mi < 4; mi++)
#pragma unroll
        for (int ni = 0; ni < 4; ni++)
          acc[mi][ni] = __builtin_amdgcn_mfma_f32_16x16x32_bf16(af[mi], bfr[ni], acc[mi][ni], 0, 0, 0);
    }
    __syncthreads();             // one barrier per K-step: drains next-tile loads too
  }

  if (isqk) {
    // acc[mi][ni] = C^T tile: rows n = col0+wn*64+ni*16+quad*4+r, col t = row0+wm*64+mi*16+l15
#pragma unroll
    for (int mi = 0; mi < 4; mi++) {
      int t = row0 + wm * 64 + mi * 16 + l15;
      int b = t >> 11, tt = t & 2047;
#pragma unroll
      for (int ni = 0; ni < 4; ni++) {
        int cN0 = col0 + wn * 64 + ni * 16 + quad * 4;
        int which = cN0 / 768;                 // 0=q, 1=k
        int rem = cN0 - which * 768;
        int h = rem >> 6, d0 = rem & 63;
        float4 bv = *reinterpret_cast<const float4*>(bias + cN0);
        float sc = which ? 1.0f : QSCALE;      // pre-scale q for shift-free exp2 softmax
        bf16x4 pack;
        pack[0] = f2bf((acc[mi][ni][0] + bv.x) * sc);
        pack[1] = f2bf((acc[mi][ni][1] + bv.y) * sc);
        pack[2] = f2bf((acc[mi][ni][2] + bv.z) * sc);
        pack[3] = f2bf((acc[mi][ni][3] + bv.w) * sc);
        bf16_t* dst = which ? kout : qout;
        *reinterpret_cast<bf16x4*>(dst + (((size_t)b * NH_ + h) * T_ + tt) * HS_ + d0) = pack;
      }
    }
  } else {
    // acc[mi][ni]: rows t = row0+wm*64+mi*16+quad*4+r, col cN = col0+wn*64+ni*16+l15 (v columns)
#pragma unroll
    for (int mi = 0; mi < 4; mi++) {
      int trow = row0 + wm * 64 + mi * 16 + quad * 4;
      int b = trow >> 11, tt = trow & 2047;       // tt % 4 == 0
      int kt = tt >> 6, nj = (tt >> 4) & 3, qd = (tt >> 2) & 3;
#pragma unroll
      for (int ni = 0; ni < 4; ni++) {
        int cN = col0 + wn * 64 + ni * 16 + l15;
        int rem = cN - 1536;
        int h = rem >> 6, d = rem & 63;
        int bh = b * NH_ + h;
        float bv = bias[cN];
        f16x4 pk;
#pragma unroll
        for (int r = 0; r < 4; r++) pk[r] = (_Float16)(acc[mi][ni][r] + bv);
        size_t off = ((((((size_t)bh * 32 + kt) * 4 + nj) * 4 + qd) * 16 + (d & 15)) * 16) + (d >> 4) * 4;
        *reinterpret_cast<f16x4*>(va + off) = pk;
      }
    }
  }
}

// ---------------- flash attention: S^T, LDS staging, uniform paired blocks, VALU-trimmed ----
// (unchanged from R13: 45.4->~43us; pair (31-p, p) = 33 tiles uniform; K 72-pitch + V
// VA-layout dbuf LDS; one barrier/tile; q pre-scaled; packed cvt; pointer-walk GLOAD)
__global__ __launch_bounds__(256) void attn_kernel(const bf16_t* __restrict__ qb,
                                                   const bf16_t* __restrict__ kb,
                                                   const _Float16* __restrict__ va,
                                                   float* __restrict__ out) {
  __shared__ bf16_t Ks[2][64][72];          // 18432 B
  __shared__ _Float16 Vs[2][4][2][64][8];   // 16384 B  [buf][ni][p][lane][e]
  const int tid = threadIdx.x;
  const int lane = tid & 63, wave = tid >> 6;
  const int quad = lane >> 4, l15 = lane & 15;
  const int pairIdx = (int)blockIdx.x;                      // 0..15
  const int bh = (int)blockIdx.z * NH_ + (int)blockIdx.y;
  const bf16_t* Qg = qb + (size_t)bh * T_ * HS_;
  const bf16_t* Kg = kb + (size_t)bh * T_ * HS_;
  const _Float16* Vg = va + (size_t)bh * 32 * 4096;         // per kt: 4096 f16

  // staging geometry (per thread: 32B of K, 32B of V)
  const int krow = tid >> 2, kcol = (tid & 3) * 16;   // K: 64 rows x 128B
  const int vni = tid >> 6, vlane = tid & 63;         // V: 4 chunks x 64 lanes x 32B

  int4 rk0, rk1, rv0, rv1;
  const char* kp;
  const char* vp;
  auto GLOAD = [&]() {                    // loads current kp/vp, then advances one tile
    rk0 = *reinterpret_cast<const int4*>(kp);
    rk1 = *reinterpret_cast<const int4*>(kp + 16);
    rv0 = *reinterpret_cast<const int4*>(vp);
    rv1 = *reinterpret_cast<const int4*>(vp + 16);
    kp += 8192; vp += 8192;
  };
  auto SSTORE = [&](int buf) {
    char* kd = (char*)&Ks[buf][krow][kcol];
    *reinterpret_cast<int4*>(kd) = rk0;
    *reinterpret_cast<int4*>(kd + 16) = rk1;
    *reinterpret_cast<int4*>(&Vs[buf][vni][0][vlane][0]) = rv0;
    *reinterpret_cast<int4*>(&Vs[buf][vni][1][vlane][0]) = rv1;
  };

#pragma unroll
  for (int part = 0; part < 2; part++) {
    const int qtile = part ? pairIdx : 31 - pairIdx;
    const int qrow_base = qtile * 64 + wave * 16;
    const int qmax = qrow_base + 15;
    const int qcol = qrow_base + l15;        // this lane's q row
    const int nkt = qtile + 1;

    // Q B-fragments (pre-scaled by QSCALE in GEMM), held across the k loop
    bf16x8 bq0 = *reinterpret_cast<const bf16x8*>(Qg + (size_t)qcol * HS_ + quad * 8);
    bf16x8 bq1 = *reinterpret_cast<const bf16x8*>(Qg + (size_t)qcol * HS_ + 32 + quad * 8);

    float lsum = 0.f;
    f32x4 Oacc[4];
#pragma unroll
    for (int mi = 0; mi < 4; mi++) Oacc[mi] = f32x4{0.f, 0.f, 0.f, 0.f};

    kp = (const char*)Kg + krow * 128 + kcol * 2;
    vp = (const char*)Vg + tid * 32;
    GLOAD();
    __syncthreads();          // all waves done reading previous part's buffers
    SSTORE(0);
    __syncthreads();

    for (int kt = 0; kt < nkt; kt++) {
      const int cur = kt & 1;
      const bool last = (kt + 1 >= nkt);
      if (!last) GLOAD();

      const bool diag = (kt == nkt - 1);
      f16x4 pf[4];
#pragma unroll
      for (int ni = 0; ni < 4; ni++) {
        if (diag && (kt * 64 + ni * 16 > qmax)) continue;
        bf16x8 ka0 = *reinterpret_cast<const bf16x8*>(&Ks[cur][ni * 16 + l15][quad * 8]);
        bf16x8 ka1 = *reinterpret_cast<const bf16x8*>(&Ks[cur][ni * 16 + l15][32 + quad * 8]);
        f32x4 s = {0.f, 0.f, 0.f, 0.f};
        s = __builtin_amdgcn_mfma_f32_16x16x32_bf16(ka0, bq0, s, 0, 0, 0);
        s = __builtin_amdgcn_mfma_f32_16x16x32_bf16(ka1, bq1, s, 0, 0, 0);
        float p0 = __builtin_amdgcn_exp2f(s[0]);
        float p1 = __builtin_amdgcn_exp2f(s[1]);
        float p2 = __builtin_amdgcn_exp2f(s[2]);
        float p3 = __builtin_amdgcn_exp2f(s[3]);
        if (diag) {
          int jb = kt * 64 + ni * 16 + quad * 4;
          if (jb + 0 > qcol) p0 = 0.f;
          if (jb + 1 > qcol) p1 = 0.f;
          if (jb + 2 > qcol) p2 = 0.f;
          if (jb + 3 > qcol) p3 = 0.f;
        }
        lsum += (p0 + p1) + (p2 + p3);
        f16x2 lo2 = __builtin_bit_cast(f16x2, __builtin_amdgcn_cvt_pkrtz(p0, p1));
        f16x2 hi2 = __builtin_bit_cast(f16x2, __builtin_amdgcn_cvt_pkrtz(p2, p3));
        pf[ni] = f16x4{lo2[0], lo2[1], hi2[0], hi2[1]};
      }
      // O^T += V^T P^T
#pragma unroll
      for (int ni = 0; ni < 4; ni++) {
        if (diag && (kt * 64 + ni * 16 > qmax)) continue;
#pragma unroll
        for (int p = 0; p < 2; p++) {
          f16x8 vv = *reinterpret_cast<const f16x8*>(&Vs[cur][ni][p][lane][0]);
          f16x4 lo = __builtin_shufflevector(vv, vv, 0, 1, 2, 3);
          f16x4 hi = __builtin_shufflevector(vv, vv, 4, 5, 6, 7);
          Oacc[2 * p]     = __builtin_amdgcn_mfma_f32_16x16x16f16(lo, pf[ni], Oacc[2 * p], 0, 0, 0);
          Oacc[2 * p + 1] = __builtin_amdgcn_mfma_f32_16x16x16f16(hi, pf[ni], Oacc[2 * p + 1], 0, 0, 0);
        }
      }

      if (!last) {
        SSTORE(1 - cur);      // compiler waits vmcnt for rk/rv here (after compute)
        __syncthreads();
      }
    }

    // lane-local lsum -> full row sum (reduce across the 4 quads)
    lsum += __shfl_xor(lsum, 16, 64);
    lsum += __shfl_xor(lsum, 32, 64);
    float rinv = 1.0f / lsum;

    // O^T tile -> out[bh][q][d], 16B stores
#pragma unroll
    for (int mi = 0; mi < 4; mi++) {
      float4 o;
      o.x = Oacc[mi][0] * rinv;
      o.y = Oacc[mi][1] * rinv;
      o.z = Oacc[mi][2] * rinv;
      o.w = Oacc[mi][3] * rinv;
      *reinterpret_cast<float4*>(out + ((size_t)bh * T_ + qcol) * HS_ + mi * 16 + quad * 4) = o;
    }
  }
}

extern "C" void kernel_launch(void* const* d_in, const int* in_sizes, int n_in,
                              void* d_out, int out_size, void* d_ws, size_t ws_size,
                              hipStream_t stream) {
  const float* x = (const float*)d_in[0];
  const float* w = (const float*)d_in[1];
  const float* bias = (const float*)d_in[2];
  float* out = (float*)d_out;

  char* ws = (char*)d_ws;
  bf16_t* xb = (bf16_t*)(ws);                            // 6,291,456 B
  bf16_t* wt = (bf16_t*)(ws + 6291456);                  // 3,538,944 B
  bf16_t* qb = (bf16_t*)(ws + 6291456 + 3538944);        // 6,291,456 B
  bf16_t* kb = qb + 3145728;                             // 6,291,456 B
  _Float16* va = (_Float16*)(kb + 3145728);              // 6,291,456 B

  cvt_xw_kernel<<<dim3(3072 + 1728), dim3(256), 0, stream>>>(x, w, xb, wt);
  gemm_qkv<<<dim3(N3_ / 128, M_ / 128), dim3(256), 0, stream>>>(xb, wt, bias, qb, kb, va);
  attn_kernel<<<dim3(16, NH_, B_), dim3(256), 0, stream>>>(qb, kb, va, out);
}

// Round 2
// 142.916 us; speedup vs baseline: 1.0285x; 1.0285x over previous
//
#include <hip/hip_runtime.h>

typedef __bf16 bf16_t;
typedef __bf16 bf16x8 __attribute__((ext_vector_type(8)));
typedef __bf16 bf16x4 __attribute__((ext_vector_type(4)));
typedef _Float16 f16x2 __attribute__((ext_vector_type(2)));
typedef _Float16 f16x4 __attribute__((ext_vector_type(4)));
typedef _Float16 f16x8 __attribute__((ext_vector_type(8)));
typedef float f32x4 __attribute__((ext_vector_type(4)));

#define B_   2
#define T_   2048
#define C_   768
#define NH_  12
#define HS_  64
#define N3_  2304
#define M_   4096
#define QSCALE 0.18033688011112042f   // 0.125 * log2(e), folded into Q at GEMM epilogue

__device__ __forceinline__ bf16_t f2bf(float f) {
  unsigned u = __builtin_bit_cast(unsigned, f);
  u += 0x7fffu + ((u >> 16) & 1u);           // round-to-nearest-even
  unsigned short s = (unsigned short)(u >> 16);
  return __builtin_bit_cast(bf16_t, s);
}

// ---------------- fused casts: x fp32->bf16, w fp32 [K][N] -> wt bf16 [N][K] ----------------
__global__ __launch_bounds__(256) void cvt_xw_kernel(const float* __restrict__ x,
                                                     const float* __restrict__ w,
                                                     bf16_t* __restrict__ xb,
                                                     bf16_t* __restrict__ wt) {
  __shared__ float tile[32][33];
  int bx = blockIdx.x;
  if (bx < 3072) {
    int i = (bx * 256 + threadIdx.x) * 4;
    float4 v = *reinterpret_cast<const float4*>(x + i);
    xb[i + 0] = f2bf(v.x);
    xb[i + 1] = f2bf(v.y);
    xb[i + 2] = f2bf(v.z);
    xb[i + 3] = f2bf(v.w);
  } else {
    int b = bx - 3072;                 // 0..1727
    int k0 = (b % 24) * 32, n0 = (b / 24) * 32;
    int tx = threadIdx.x & 31, ty = threadIdx.x >> 5;   // 32 x 8
#pragma unroll
    for (int i = 0; i < 4; i++)
      tile[ty + i * 8][tx] = w[(size_t)(k0 + ty + i * 8) * N3_ + n0 + tx];
    __syncthreads();
#pragma unroll
    for (int i = 0; i < 4; i++)
      wt[(size_t)(n0 + ty + i * 8) * C_ + k0 + tx] = f2bf(tile[tx][ty + i * 8]);
  }
}

// ---------------- qkv GEMM: 64x128 tile for grid-level parallelism -------------------------
// R15: R14's 2-phase pipeline was NEUTRAL -> intra-block schedule is not the binding
// constraint. Evidence: m97-structure scales 320 TF @1 block/CU -> 874 TF @4 blocks/CU;
// we had grid=576 (2.25/CU) with VGPR ~170 capping residency at ~3. Halving the M-tile
// to 64x128 gives grid=1152 (4.5/CU), acc 64->32 VGPRs, LDS 32->24 KiB, so 4-5 blocks
// co-reside and cross-block wave overlap (m114) absorbs the per-step vmcnt(0) drains.
// Accumulation order per output unchanged -> bitwise-identical results.
// q/k blocks: swapped operands -> C^T tiles -> 8B packed [t][d] stores, q pre-scaled.
// v blocks: normal -> f16 MFMA-native VA layout for attn PV A-operand.
__global__ __launch_bounds__(256) void gemm_qkv(const bf16_t* __restrict__ xb,
                                                const bf16_t* __restrict__ wt,
                                                const float* __restrict__ bias,
                                                bf16_t* __restrict__ qout,
                                                bf16_t* __restrict__ kout,
                                                _Float16* __restrict__ va) {
  __shared__ bf16_t As[2][64 * 32];    // [buf][m][k] panel, flat, no pad (64B rows)
  __shared__ bf16_t Bs[2][128 * 32];
  const int tid = threadIdx.x;
  const int lane = tid & 63, wave = tid >> 6;
  const int wm = wave >> 1, wn = wave & 1;   // 2(M) x 2(N) waves; wave tile 32x64
  const int quad = lane >> 4, l15 = lane & 15;
  const int row0 = blockIdx.y * 64;
  const int col0 = blockIdx.x * 128;
  const bool isqk = (col0 < 1536);

  f32x4 acc[2][4];
#pragma unroll
  for (int mi = 0; mi < 2; mi++)
#pragma unroll
    for (int ni = 0; ni < 4; ni++) acc[mi][ni] = f32x4{0.f, 0.f, 0.f, 0.f};

  // staging: A tile = 64x32 bf16 = 4 KiB = 256 x 16B chunks (1/thread);
  //          B tile = 128x32 = 8 KiB = 512 chunks (2/thread: tid, 256+tid).
  // chunk n -> LDS row n>>2, 8-col group n&3; glds dest = wave-uniform base + lane*16.
  const int r0 = tid >> 2, q0 = tid & 3;
  const int r1 = (256 + tid) >> 2, q1 = (256 + tid) & 3;
  const bf16_t* gA0 = xb + (size_t)(row0 + r0) * C_ + q0 * 8;
  const bf16_t* gB0 = wt + (size_t)(col0 + r0) * C_ + q0 * 8;
  const bf16_t* gB1 = wt + (size_t)(col0 + r1) * C_ + q1 * 8;
  const int ldsOff0 = (wave * 64) * 16;          // chunk block c=0
  const int ldsOff1 = (256 + wave * 64) * 16;    // chunk block c=1

  auto STAGE = [&](int buf, int k0) {
    __builtin_amdgcn_global_load_lds((const __attribute__((address_space(1))) void*)(gA0 + k0),
                                     (__attribute__((address_space(3))) void*)((char*)As[buf] + ldsOff0), 16, 0, 0);
    __builtin_amdgcn_global_load_lds((const __attribute__((address_space(1))) void*)(gB0 + k0),
                                     (__attribute__((address_space(3))) void*)((char*)Bs[buf] + ldsOff0), 16, 0, 0);
    __builtin_amdgcn_global_load_lds((const __attribute__((address_space(1))) void*)(gB1 + k0),
                                     (__attribute__((address_space(3))) void*)((char*)Bs[buf] + ldsOff1), 16, 0, 0);
  };

  STAGE(0, 0);
  __syncthreads();               // drain prologue loads

  constexpr int NT = C_ / 32;    // 24 K-steps
#pragma unroll 2
  for (int t = 0; t < NT; ++t) {
    const int cur = t & 1;
    if (t + 1 < NT) STAGE(cur ^ 1, (t + 1) * 32);   // issue next-tile loads FIRST

    bf16x8 af[2], bfr[4];
#pragma unroll
    for (int mi = 0; mi < 2; mi++)
      af[mi] = *reinterpret_cast<const bf16x8*>(&As[cur][(wm * 32 + mi * 16 + l15) * 32 + quad * 8]);
#pragma unroll
    for (int ni = 0; ni < 4; ni++)
      bfr[ni] = *reinterpret_cast<const bf16x8*>(&Bs[cur][(wn * 64 + ni * 16 + l15) * 32 + quad * 8]);
    if (isqk) {
#pragma unroll
      for (int mi = 0; mi < 2; mi++)
#pragma unroll
        for (int ni = 0; ni < 4; ni++)
          acc[mi][ni] = __builtin_amdgcn_mfma_f32_16x16x32_bf16(bfr[ni], af[mi], acc[mi][ni], 0, 0, 0);
    } else {
#pragma unroll
      for (int mi = 0; mi < 2; mi++)
#pragma unroll
        for (int ni = 0; ni < 4; ni++)
          acc[mi][ni] = __builtin_amdgcn_mfma_f32_16x16x32_bf16(af[mi], bfr[ni], acc[mi][ni], 0, 0, 0);
    }
    __syncthreads();             // one barrier per K-step: drains next-tile loads too
  }

  if (isqk) {
    // acc[mi][ni] = C^T tile: rows n = col0+wn*64+ni*16+quad*4+r, col t = row0+wm*32+mi*16+l15
#pragma unroll
    for (int mi = 0; mi < 2; mi++) {
      int t = row0 + wm * 32 + mi * 16 + l15;
      int b = t >> 11, tt = t & 2047;
#pragma unroll
      for (int ni = 0; ni < 4; ni++) {
        int cN0 = col0 + wn * 64 + ni * 16 + quad * 4;
        int which = cN0 / 768;                 // 0=q, 1=k
        int rem = cN0 - which * 768;
        int h = rem >> 6, d0 = rem & 63;
        float4 bv = *reinterpret_cast<const float4*>(bias + cN0);
        float sc = which ? 1.0f : QSCALE;      // pre-scale q for shift-free exp2 softmax
        bf16x4 pack;
        pack[0] = f2bf((acc[mi][ni][0] + bv.x) * sc);
        pack[1] = f2bf((acc[mi][ni][1] + bv.y) * sc);
        pack[2] = f2bf((acc[mi][ni][2] + bv.z) * sc);
        pack[3] = f2bf((acc[mi][ni][3] + bv.w) * sc);
        bf16_t* dst = which ? kout : qout;
        *reinterpret_cast<bf16x4*>(dst + (((size_t)b * NH_ + h) * T_ + tt) * HS_ + d0) = pack;
      }
    }
  } else {
    // acc[mi][ni]: rows t = row0+wm*32+mi*16+quad*4+r, col cN = col0+wn*64+ni*16+l15 (v columns)
#pragma unroll
    for (int mi = 0; mi < 2; mi++) {
      int trow = row0 + wm * 32 + mi * 16 + quad * 4;
      int b = trow >> 11, tt = trow & 2047;       // tt % 4 == 0
      int kt = tt >> 6, nj = (tt >> 4) & 3, qd = (tt >> 2) & 3;
#pragma unroll
      for (int ni = 0; ni < 4; ni++) {
        int cN = col0 + wn * 64 + ni * 16 + l15;
        int rem = cN - 1536;
        int h = rem >> 6, d = rem & 63;
        int bh = b * NH_ + h;
        float bv = bias[cN];
        f16x4 pk;
#pragma unroll
        for (int r = 0; r < 4; r++) pk[r] = (_Float16)(acc[mi][ni][r] + bv);
        size_t off = ((((((size_t)bh * 32 + kt) * 4 + nj) * 4 + qd) * 16 + (d & 15)) * 16) + (d >> 4) * 4;
        *reinterpret_cast<f16x4*>(va + off) = pk;
      }
    }
  }
}

// ---------------- flash attention: S^T, LDS staging, uniform paired blocks, VALU-trimmed ----
// (unchanged from R13: 45.4->~43us; pair (31-p, p) = 33 tiles uniform; K 72-pitch + V
// VA-layout dbuf LDS; one barrier/tile; q pre-scaled; packed cvt; pointer-walk GLOAD)
__global__ __launch_bounds__(256) void attn_kernel(const bf16_t* __restrict__ qb,
                                                   const bf16_t* __restrict__ kb,
                                                   const _Float16* __restrict__ va,
                                                   float* __restrict__ out) {
  __shared__ bf16_t Ks[2][64][72];          // 18432 B
  __shared__ _Float16 Vs[2][4][2][64][8];   // 16384 B  [buf][ni][p][lane][e]
  const int tid = threadIdx.x;
  const int lane = tid & 63, wave = tid >> 6;
  const int quad = lane >> 4, l15 = lane & 15;
  const int pairIdx = (int)blockIdx.x;                      // 0..15
  const int bh = (int)blockIdx.z * NH_ + (int)blockIdx.y;
  const bf16_t* Qg = qb + (size_t)bh * T_ * HS_;
  const bf16_t* Kg = kb + (size_t)bh * T_ * HS_;
  const _Float16* Vg = va + (size_t)bh * 32 * 4096;         // per kt: 4096 f16

  // staging geometry (per thread: 32B of K, 32B of V)
  const int krow = tid >> 2, kcol = (tid & 3) * 16;   // K: 64 rows x 128B
  const int vni = tid >> 6, vlane = tid & 63;         // V: 4 chunks x 64 lanes x 32B

  int4 rk0, rk1, rv0, rv1;
  const char* kp;
  const char* vp;
  auto GLOAD = [&]() {                    // loads current kp/vp, then advances one tile
    rk0 = *reinterpret_cast<const int4*>(kp);
    rk1 = *reinterpret_cast<const int4*>(kp + 16);
    rv0 = *reinterpret_cast<const int4*>(vp);
    rv1 = *reinterpret_cast<const int4*>(vp + 16);
    kp += 8192; vp += 8192;
  };
  auto SSTORE = [&](int buf) {
    char* kd = (char*)&Ks[buf][krow][kcol];
    *reinterpret_cast<int4*>(kd) = rk0;
    *reinterpret_cast<int4*>(kd + 16) = rk1;
    *reinterpret_cast<int4*>(&Vs[buf][vni][0][vlane][0]) = rv0;
    *reinterpret_cast<int4*>(&Vs[buf][vni][1][vlane][0]) = rv1;
  };

#pragma unroll
  for (int part = 0; part < 2; part++) {
    const int qtile = part ? pairIdx : 31 - pairIdx;
    const int qrow_base = qtile * 64 + wave * 16;
    const int qmax = qrow_base + 15;
    const int qcol = qrow_base + l15;        // this lane's q row
    const int nkt = qtile + 1;

    // Q B-fragments (pre-scaled by QSCALE in GEMM), held across the k loop
    bf16x8 bq0 = *reinterpret_cast<const bf16x8*>(Qg + (size_t)qcol * HS_ + quad * 8);
    bf16x8 bq1 = *reinterpret_cast<const bf16x8*>(Qg + (size_t)qcol * HS_ + 32 + quad * 8);

    float lsum = 0.f;
    f32x4 Oacc[4];
#pragma unroll
    for (int mi = 0; mi < 4; mi++) Oacc[mi] = f32x4{0.f, 0.f, 0.f, 0.f};

    kp = (const char*)Kg + krow * 128 + kcol * 2;
    vp = (const char*)Vg + tid * 32;
    GLOAD();
    __syncthreads();          // all waves done reading previous part's buffers
    SSTORE(0);
    __syncthreads();

    for (int kt = 0; kt < nkt; kt++) {
      const int cur = kt & 1;
      const bool last = (kt + 1 >= nkt);
      if (!last) GLOAD();

      const bool diag = (kt == nkt - 1);
      f16x4 pf[4];
#pragma unroll
      for (int ni = 0; ni < 4; ni++) {
        if (diag && (kt * 64 + ni * 16 > qmax)) continue;
        bf16x8 ka0 = *reinterpret_cast<const bf16x8*>(&Ks[cur][ni * 16 + l15][quad * 8]);
        bf16x8 ka1 = *reinterpret_cast<const bf16x8*>(&Ks[cur][ni * 16 + l15][32 + quad * 8]);
        f32x4 s = {0.f, 0.f, 0.f, 0.f};
        s = __builtin_amdgcn_mfma_f32_16x16x32_bf16(ka0, bq0, s, 0, 0, 0);
        s = __builtin_amdgcn_mfma_f32_16x16x32_bf16(ka1, bq1, s, 0, 0, 0);
        float p0 = __builtin_amdgcn_exp2f(s[0]);
        float p1 = __builtin_amdgcn_exp2f(s[1]);
        float p2 = __builtin_amdgcn_exp2f(s[2]);
        float p3 = __builtin_amdgcn_exp2f(s[3]);
        if (diag) {
          int jb = kt * 64 + ni * 16 + quad * 4;
          if (jb + 0 > qcol) p0 = 0.f;
          if (jb + 1 > qcol) p1 = 0.f;
          if (jb + 2 > qcol) p2 = 0.f;
          if (jb + 3 > qcol) p3 = 0.f;
        }
        lsum += (p0 + p1) + (p2 + p3);
        f16x2 lo2 = __builtin_bit_cast(f16x2, __builtin_amdgcn_cvt_pkrtz(p0, p1));
        f16x2 hi2 = __builtin_bit_cast(f16x2, __builtin_amdgcn_cvt_pkrtz(p2, p3));
        pf[ni] = f16x4{lo2[0], lo2[1], hi2[0], hi2[1]};
      }
      // O^T += V^T P^T
#pragma unroll
      for (int ni = 0; ni < 4; ni++) {
        if (diag && (kt * 64 + ni * 16 > qmax)) continue;
#pragma unroll
        for (int p = 0; p < 2; p++) {
          f16x8 vv = *reinterpret_cast<const f16x8*>(&Vs[cur][ni][p][lane][0]);
          f16x4 lo = __builtin_shufflevector(vv, vv, 0, 1, 2, 3);
          f16x4 hi = __builtin_shufflevector(vv, vv, 4, 5, 6, 7);
          Oacc[2 * p]     = __builtin_amdgcn_mfma_f32_16x16x16f16(lo, pf[ni], Oacc[2 * p], 0, 0, 0);
          Oacc[2 * p + 1] = __builtin_amdgcn_mfma_f32_16x16x16f16(hi, pf[ni], Oacc[2 * p + 1], 0, 0, 0);
        }
      }

      if (!last) {
        SSTORE(1 - cur);      // compiler waits vmcnt for rk/rv here (after compute)
        __syncthreads();
      }
    }

    // lane-local lsum -> full row sum (reduce across the 4 quads)
    lsum += __shfl_xor(lsum, 16, 64);
    lsum += __shfl_xor(lsum, 32, 64);
    float rinv = 1.0f / lsum;

    // O^T tile -> out[bh][q][d], 16B stores
#pragma unroll
    for (int mi = 0; mi < 4; mi++) {
      float4 o;
      o.x = Oacc[mi][0] * rinv;
      o.y = Oacc[mi][1] * rinv;
      o.z = Oacc[mi][2] * rinv;
      o.w = Oacc[mi][3] * rinv;
      *reinterpret_cast<float4*>(out + ((size_t)bh * T_ + qcol) * HS_ + mi * 16 + quad * 4) = o;
    }
  }
}

extern "C" void kernel_launch(void* const* d_in, const int* in_sizes, int n_in,
                              void* d_out, int out_size, void* d_ws, size_t ws_size,
                              hipStream_t stream) {
  const float* x = (const float*)d_in[0];
  const float* w = (const float*)d_in[1];
  const float* bias = (const float*)d_in[2];
  float* out = (float*)d_out;

  char* ws = (char*)d_ws;
  bf16_t* xb = (bf16_t*)(ws);                            // 6,291,456 B
  bf16_t* wt = (bf16_t*)(ws + 6291456);                  // 3,538,944 B
  bf16_t* qb = (bf16_t*)(ws + 6291456 + 3538944);        // 6,291,456 B
  bf16_t* kb = qb + 3145728;                             // 6,291,456 B
  _Float16* va = (_Float16*)(kb + 3145728);              // 6,291,456 B

  cvt_xw_kernel<<<dim3(3072 + 1728), dim3(256), 0, stream>>>(x, w, xb, wt);
  gemm_qkv<<<dim3(N3_ / 128, M_ / 64), dim3(256), 0, stream>>>(xb, wt, bias, qb, kb, va);
  attn_kernel<<<dim3(16, NH_, B_), dim3(256), 0, stream>>>(qb, kb, va, out);
}